// Round 16
// baseline (109.346 us; speedup 1.0000x reference)
//
#include <hip/hip_runtime.h>
#include <hip/hip_bf16.h>
#include <stdint.h>

typedef __attribute__((ext_vector_type(8))) short bf16x8;
typedef __attribute__((ext_vector_type(8))) short short8;
typedef __attribute__((ext_vector_type(4))) float f32x4;

#define M_DIM 512
#define N_DIM 4096
#define K_DIM 11008
#define KSTEPS 172   // K_DIM / 64

#define GLOBAL_AS(p) ((const __attribute__((address_space(1))) void*)(p))
#define LDS_AS(p)    ((__attribute__((address_space(3))) void*)(p))

// round-to-nearest-even fp32 -> bf16 bits
__device__ __forceinline__ short f2bf(float f) {
    unsigned u = __float_as_uint(f);
    unsigned r = u + 0x7fff + ((u >> 16) & 1);
    return (short)(r >> 16);
}

__device__ __forceinline__ unsigned cvt_pk_bf16(float lo, float hi) {
    unsigned r;
    asm("v_cvt_pk_bf16_f32 %0, %1, %2" : "=v"(r) : "v"(lo), "v"(hi));
    return r;
}

// pure-VALU DPP quad exchanges
__device__ __forceinline__ float dpp_xor1(float v) {   // quad_perm [1,0,3,2]
    return __int_as_float(__builtin_amdgcn_mov_dpp(__float_as_int(v), 0xB1, 0xf, 0xf, true));
}
__device__ __forceinline__ float dpp_xor2(float v) {   // quad_perm [2,3,0,1]
    return __int_as_float(__builtin_amdgcn_mov_dpp(__float_as_int(v), 0x4E, 0xf, 0xf, true));
}

__device__ __forceinline__ void fence_bar() {
    asm volatile("" ::: "memory");
    __builtin_amdgcn_s_barrier();
    asm volatile("" ::: "memory");
}
#define LGKM0() asm volatile("s_waitcnt lgkmcnt(0)" ::: "memory")
#define VMCNT(n) asm volatile("s_waitcnt vmcnt(" #n ")" ::: "memory")

// ---------------- Kernel 1: x fp32 -> bf16 ----------------
__global__ __launch_bounds__(256) void conv_x(const float* __restrict__ x, short* __restrict__ xb) {
    const long long total = (long long)M_DIM * K_DIM;
    for (long long e0 = ((long long)blockIdx.x * 256 + threadIdx.x) * 8;
         e0 < total;
         e0 += (long long)gridDim.x * 256 * 8) {
        const float4* p = (const float4*)(x + e0);
        float4 v0 = p[0];
        float4 v1 = p[1];
        short8 s;
        s[0] = f2bf(v0.x); s[1] = f2bf(v0.y); s[2] = f2bf(v0.z); s[3] = f2bf(v0.w);
        s[4] = f2bf(v1.x); s[5] = f2bf(v1.y); s[6] = f2bf(v1.z); s[7] = f2bf(v1.w);
        *(short8*)(xb + e0) = s;
    }
}

// ---------------- Kernel 2: fused fake-quant + 256x128 bf16 GEMM (R15 base, splitk=4) ----------------
// R15's proven dataflow unchanged: A coalesced global_load_lds double-buffer (64KB);
// B = W fp32 reg-staged -> quad-reduce quant -> single-buffer Bs (16KB); two barriers/tile;
// 8 waves (4M x 2N), per-wave C 64x64 -> acc 64 AGPR, VGPR 64.
// Only change vs R15: splitk 8 -> 4 (occupancy proven irrelevant; halves partial traffic).
__global__ __launch_bounds__(512, 4) void gemm_fq(const short* __restrict__ A,
                                                  const float* __restrict__ W,
                                                  unsigned short* __restrict__ P,
                                                  int spb) {
    __shared__ short As[2][256 * 64];
    __shared__ short Bs[128 * 64];
    const int tid  = threadIdx.x;
    const int lane = tid & 63;
    const int w    = tid >> 6;   // 0..7
    const int wr   = w >> 1;     // 0..3 (M)
    const int wc   = w & 1;      // 0..1 (N)
    const int m0   = blockIdx.y * 256;
    const int n0   = blockIdx.x * 128;
    const int kt0  = blockIdx.z * spb;
    const int kt1  = min(kt0 + spb, KSTEPS);   // every split >= 2 tiles by construction

    const int srow = lane >> 3;                      // 0..7 (A staging row within 8-row chunk)
    const int sswz = (lane & 7) ^ srow;              // A staging source swizzle
    const int rC   = tid >> 2;                       // 0..127: B row (4 lanes per row, one quad)
    const int qC   = tid & 3;                        // quarter (16 floats) of the 64-group
    const int arow = wr * 64 + (lane & 15);
    const int brow = wc * 64 + (lane & 15);
    const int qb   = lane >> 4;

    f32x4  acc[4][4] = {};
    float4 C[4];   // one quarter-row of W (16 floats), static indexing

    auto stageA = [&](int d, int kt) {
        #pragma unroll
        for (int i = 0; i < 4; ++i) {
            const int rb = (w * 4 + i) * 8;          // 8 rows per instruction per wave
            __builtin_amdgcn_global_load_lds(
                GLOBAL_AS(A + (size_t)(m0 + rb + srow) * K_DIM + kt * 64 + sswz * 8),
                LDS_AS(&As[d][rb * 64]), 16, 0, 0);
        }
    };
    auto loadC = [&](int kt) {
        const float4* src = (const float4*)(W + (size_t)(n0 + rC) * K_DIM + (size_t)kt * 64 + qC * 16);
        #pragma unroll
        for (int j = 0; j < 4; ++j) C[j] = src[j];
    };
    auto quantC = [&]() {
        const float* pv = (const float*)&C[0];
        float mns[8], mxs[8];
        #pragma unroll
        for (int j = 0; j < 8; ++j) {
            mns[j] = fminf(pv[2 * j], pv[2 * j + 1]);
            mxs[j] = fmaxf(pv[2 * j], pv[2 * j + 1]);
        }
        #pragma unroll
        for (int st = 4; st >= 1; st >>= 1)
            #pragma unroll
            for (int j = 0; j < st; ++j) {
                mns[j] = fminf(mns[j], mns[j + st]);
                mxs[j] = fmaxf(mxs[j], mxs[j + st]);
            }
        // 4 quarter-threads of one row live in one DPP quad: pure-VALU group reduce
        float mn = fminf(mns[0], dpp_xor1(mns[0]));
        mn = fminf(mn, dpp_xor2(mn));
        float mx = fmaxf(mxs[0], dpp_xor1(mxs[0]));
        mx = fmaxf(mx, dpp_xor2(mx));
        float range = fmaxf(mx - mn, 1e-5f);
        float scale = range * (1.0f / 15.0f);
        float rs    = 1.0f / scale;   // one precise div per thread per tile
        // zero-point cancels: w_dq = rint(w/s)*s when no clipping; clamp redundant (proven R6-R15)
        const int base = rC * 64;
        #pragma unroll
        for (int s4 = 0; s4 < 2; ++s4) {
            float q[8];
            #pragma unroll
            for (int j = 0; j < 8; ++j)
                q[j] = rintf(pv[s4 * 8 + j] * rs) * scale;
            union { unsigned u[4]; short8 s; } pk;
            #pragma unroll
            for (int j = 0; j < 4; ++j)
                pk.u[j] = cvt_pk_bf16(q[2 * j], q[2 * j + 1]);
            const int s = qC * 2 + s4;   // 8-elem slot 0..7
            *(short8*)&Bs[base + ((s ^ (rC & 7)) * 8)] = pk.s;
        }
    };

    // ---- prologue ----
    loadC(kt0);                                // +4
    stageA(0, kt0);                            // +4
    VMCNT(4);  quantC();                       // C(kt0) landed (A:4 outstanding)
    loadC(kt0 + 1);                            // +4
    VMCNT(4);                                  // A(kt0) landed; queue = [C':4]
    LGKM0();
    fence_bar();

    int par = 0;
    for (int t = kt0; t < kt1; ++t) {
        const int tn  = (t + 1 < kt1) ? t + 1 : t;        // A stage target (dummy on last)
        const int tn2 = (t + 2 < kt1) ? t + 2 : kt1 - 1;  // C loads (dummy on tail)
        const short* Asc = As[par];

        // issue A(t+1) staging first: full-tile latency slack
        stageA(par ^ 1, tn);         // queue = [C(t+1):4, A:4]

        // ---- MFMA region: As[par] + Bs (single buffer), 32 MFMA/wave ----
        #pragma unroll
        for (int ks = 0; ks < 2; ++ks) {
            bf16x8 bfr[4];
            #pragma unroll
            for (int fn = 0; fn < 4; ++fn) {
                const int r = brow + fn * 16;
                bfr[fn] = *(const bf16x8*)&Bs[r * 64 + (((ks * 4 + qb) ^ (r & 7)) * 8)];
            }
            #pragma unroll
            for (int fm = 0; fm < 4; ++fm) {
                const int r = arow + fm * 16;
                bf16x8 af = *(const bf16x8*)&Asc[r * 64 + (((ks * 4 + qb) ^ (r & 7)) * 8)];
                #pragma unroll
                for (int fn = 0; fn < 4; ++fn)
                    acc[fm][fn] = __builtin_amdgcn_mfma_f32_16x16x32_bf16(
                        af, bfr[fn], acc[fm][fn], 0, 0, 0);
            }
        }
        fence_bar();                 // barrier1: Bs readers done block-wide

        // ---- quant region: write B(t+1) into Bs ----
        VMCNT(4);                    // C(t+1) landed (issued a full tile ago; leaves A:4)
        quantC();
        loadC(tn2);                  // +4
        VMCNT(4);                    // A(t+1) landed (issued at tile top; leaves C(t+2):4)
        LGKM0();                     // quant ds_writes drained
        fence_bar();                 // barrier2: Bs(t+1) + As[par^1] ready
        par ^= 1;
    }

    VMCNT(0);   // drain dummy tail loads

    unsigned short* out = P + (size_t)blockIdx.z * M_DIM * N_DIM;
    #pragma unroll
    for (int fm = 0; fm < 4; ++fm) {
        #pragma unroll
        for (int fn = 0; fn < 4; ++fn) {
            const int col  = n0 + wc * 64 + fn * 16 + (lane & 15);
            const int rowb = m0 + wr * 64 + fm * 16 + (lane >> 4) * 4;
            #pragma unroll
            for (int r = 0; r < 4; ++r) {
                out[(size_t)(rowb + r) * N_DIM + col] = (unsigned short)f2bf(acc[fm][fn][r]);
            }
        }
    }
}

// ---------------- Kernel 3: reduce bf16 split-K partials + bias ----------------
__global__ __launch_bounds__(256) void reduce_out(const unsigned short* __restrict__ P,
                                                  const float* __restrict__ bias,
                                                  float* __restrict__ out,
                                                  int splitk) {
    const size_t total = (size_t)M_DIM * N_DIM;
    for (size_t idx8 = ((size_t)blockIdx.x * 256 + threadIdx.x) * 8;
         idx8 < total;
         idx8 += (size_t)gridDim.x * 256 * 8) {
        const int col = (int)(idx8 % N_DIM);
        float s[8];
        {
            float4 b0 = *(const float4*)(bias + col);
            float4 b1 = *(const float4*)(bias + col + 4);
            s[0] = b0.x; s[1] = b0.y; s[2] = b0.z; s[3] = b0.w;
            s[4] = b1.x; s[5] = b1.y; s[6] = b1.z; s[7] = b1.w;
        }
        for (int sp = 0; sp < splitk; ++sp) {
            short8 p = *(const short8*)(P + (size_t)sp * total + idx8);
            #pragma unroll
            for (int j = 0; j < 8; ++j)
                s[j] += __uint_as_float(((unsigned)(unsigned short)p[j]) << 16);
        }
        float4 o0 = {s[0], s[1], s[2], s[3]};
        float4 o1 = {s[4], s[5], s[6], s[7]};
        *(float4*)(out + idx8) = o0;
        *(float4*)(out + idx8 + 4) = o1;
    }
}

extern "C" void kernel_launch(void* const* d_in, const int* in_sizes, int n_in,
                              void* d_out, int out_size, void* d_ws, size_t ws_size,
                              hipStream_t stream) {
    const float* x    = (const float*)d_in[0];
    const float* wgt  = (const float*)d_in[1];
    const float* bias = (const float*)d_in[2];
    float* out = (float*)d_out;

    char* ws = (char*)d_ws;
    const size_t xb_bytes = (size_t)M_DIM * K_DIM * 2;          // 11,272,192
    short* xb = (short*)ws;
    unsigned short* part = (unsigned short*)(ws + xb_bytes);

    const size_t per_split = (size_t)M_DIM * N_DIM * 2;         // 4 MiB (bf16)
    size_t avail = (ws_size > xb_bytes) ? (ws_size - xb_bytes) : 0;
    // largest splitk in [1,4] that fits, with every split >= 2 K-tiles
    // (splitk=4 halves partial traffic vs 8; occupancy proven irrelevant R13/R15)
    int splitk = 1, spb = KSTEPS;
    for (int sk = 4; sk >= 1; --sk) {
        if ((size_t)sk * per_split > avail) continue;
        int s = (KSTEPS + sk - 1) / sk;
        int last = KSTEPS - (sk - 1) * s;
        if (last < 2) continue;
        splitk = sk; spb = s;
        break;
    }

    hipLaunchKernelGGL(conv_x, dim3(2048), dim3(256), 0, stream, x, xb);
    hipLaunchKernelGGL(gemm_fq, dim3(N_DIM / 128, M_DIM / 256, splitk), dim3(512), 0, stream,
                       xb, wgt, part, spb);
    hipLaunchKernelGGL(reduce_out, dim3(2048), dim3(256), 0, stream, part, bias, out, splitk);
}

// Round 17
// 93.913 us; speedup vs baseline: 1.1643x; 1.1643x over previous
//
#include <hip/hip_runtime.h>
#include <hip/hip_bf16.h>
#include <stdint.h>

typedef __attribute__((ext_vector_type(8))) short bf16x8;
typedef __attribute__((ext_vector_type(8))) short short8;
typedef __attribute__((ext_vector_type(4))) float f32x4;

#define M_DIM 512
#define N_DIM 4096
#define K_DIM 11008
#define KSTEPS 172   // K_DIM / 64

#define GLOBAL_AS(p) ((const __attribute__((address_space(1))) void*)(p))
#define LDS_AS(p)    ((__attribute__((address_space(3))) void*)(p))

// round-to-nearest-even fp32 -> bf16 bits
__device__ __forceinline__ short f2bf(float f) {
    unsigned u = __float_as_uint(f);
    unsigned r = u + 0x7fff + ((u >> 16) & 1);
    return (short)(r >> 16);
}

__device__ __forceinline__ unsigned cvt_pk_bf16(float lo, float hi) {
    unsigned r;
    asm("v_cvt_pk_bf16_f32 %0, %1, %2" : "=v"(r) : "v"(lo), "v"(hi));
    return r;
}

// pure-VALU DPP quad exchanges
__device__ __forceinline__ float dpp_xor1(float v) {   // quad_perm [1,0,3,2]
    return __int_as_float(__builtin_amdgcn_mov_dpp(__float_as_int(v), 0xB1, 0xf, 0xf, true));
}
__device__ __forceinline__ float dpp_xor2(float v) {   // quad_perm [2,3,0,1]
    return __int_as_float(__builtin_amdgcn_mov_dpp(__float_as_int(v), 0x4E, 0xf, 0xf, true));
}

__device__ __forceinline__ void fence_bar() {
    asm volatile("" ::: "memory");
    __builtin_amdgcn_s_barrier();
    asm volatile("" ::: "memory");
}
#define LGKM0() asm volatile("s_waitcnt lgkmcnt(0)" ::: "memory")
#define VMCNT(n) asm volatile("s_waitcnt vmcnt(" #n ")" ::: "memory")

// ---------------- Kernel 1: x fp32 -> bf16 ----------------
__global__ __launch_bounds__(256) void conv_x(const float* __restrict__ x, short* __restrict__ xb) {
    const long long total = (long long)M_DIM * K_DIM;
    for (long long e0 = ((long long)blockIdx.x * 256 + threadIdx.x) * 8;
         e0 < total;
         e0 += (long long)gridDim.x * 256 * 8) {
        const float4* p = (const float4*)(x + e0);
        float4 v0 = p[0];
        float4 v1 = p[1];
        short8 s;
        s[0] = f2bf(v0.x); s[1] = f2bf(v0.y); s[2] = f2bf(v0.z); s[3] = f2bf(v0.w);
        s[4] = f2bf(v1.x); s[5] = f2bf(v1.y); s[6] = f2bf(v1.z); s[7] = f2bf(v1.w);
        *(short8*)(xb + e0) = s;
    }
}

// ---------------- Kernel 2: fused fake-quant + 256x128 bf16 GEMM (R15, best known) ----------------
// A: coalesced global_load_lds double-buffer (64KB), XOR-swizzled source.
// B: W fp32 reg-staged (thread = quarter-row, one DPP quad per row) -> pure-VALU quad reduce
//    -> quant -> single-buffer Bs (16KB). Two barriers/tile.
// 8 waves (4M x 2N), per-wave C 64x64 -> acc 64 AGPR, VGPR 64.
// splitk=8 -> 512 blocks = 2 blocks/CU: necessary AND sufficient (R16: 1 block/CU costs 20%;
// R13: >2 blocks/CU gains nothing). LDS 80KB caps at exactly 2.
__global__ __launch_bounds__(512, 4) void gemm_fq(const short* __restrict__ A,
                                                  const float* __restrict__ W,
                                                  unsigned short* __restrict__ P,
                                                  int spb) {
    __shared__ short As[2][256 * 64];
    __shared__ short Bs[128 * 64];
    const int tid  = threadIdx.x;
    const int lane = tid & 63;
    const int w    = tid >> 6;   // 0..7
    const int wr   = w >> 1;     // 0..3 (M)
    const int wc   = w & 1;      // 0..1 (N)
    const int m0   = blockIdx.y * 256;
    const int n0   = blockIdx.x * 128;
    const int kt0  = blockIdx.z * spb;
    const int kt1  = min(kt0 + spb, KSTEPS);   // every split >= 2 tiles by construction

    const int srow = lane >> 3;                      // 0..7 (A staging row within 8-row chunk)
    const int sswz = (lane & 7) ^ srow;              // A staging source swizzle
    const int rC   = tid >> 2;                       // 0..127: B row (4 lanes per row, one quad)
    const int qC   = tid & 3;                        // quarter (16 floats) of the 64-group
    const int arow = wr * 64 + (lane & 15);
    const int brow = wc * 64 + (lane & 15);
    const int qb   = lane >> 4;

    f32x4  acc[4][4] = {};
    float4 C[4];   // one quarter-row of W (16 floats), static indexing

    auto stageA = [&](int d, int kt) {
        #pragma unroll
        for (int i = 0; i < 4; ++i) {
            const int rb = (w * 4 + i) * 8;          // 8 rows per instruction per wave
            __builtin_amdgcn_global_load_lds(
                GLOBAL_AS(A + (size_t)(m0 + rb + srow) * K_DIM + kt * 64 + sswz * 8),
                LDS_AS(&As[d][rb * 64]), 16, 0, 0);
        }
    };
    auto loadC = [&](int kt) {
        const float4* src = (const float4*)(W + (size_t)(n0 + rC) * K_DIM + (size_t)kt * 64 + qC * 16);
        #pragma unroll
        for (int j = 0; j < 4; ++j) C[j] = src[j];
    };
    auto quantC = [&]() {
        const float* pv = (const float*)&C[0];
        float mns[8], mxs[8];
        #pragma unroll
        for (int j = 0; j < 8; ++j) {
            mns[j] = fminf(pv[2 * j], pv[2 * j + 1]);
            mxs[j] = fmaxf(pv[2 * j], pv[2 * j + 1]);
        }
        #pragma unroll
        for (int st = 4; st >= 1; st >>= 1)
            #pragma unroll
            for (int j = 0; j < st; ++j) {
                mns[j] = fminf(mns[j], mns[j + st]);
                mxs[j] = fmaxf(mxs[j], mxs[j + st]);
            }
        // 4 quarter-threads of one row live in one DPP quad: pure-VALU group reduce
        float mn = fminf(mns[0], dpp_xor1(mns[0]));
        mn = fminf(mn, dpp_xor2(mn));
        float mx = fmaxf(mxs[0], dpp_xor1(mxs[0]));
        mx = fmaxf(mx, dpp_xor2(mx));
        float range = fmaxf(mx - mn, 1e-5f);
        float scale = range * (1.0f / 15.0f);
        float rs    = 1.0f / scale;   // one precise div per thread per tile
        // zero-point cancels: w_dq = rint(w/s)*s when no clipping; clamp redundant (proven R6-R16)
        const int base = rC * 64;
        #pragma unroll
        for (int s4 = 0; s4 < 2; ++s4) {
            float q[8];
            #pragma unroll
            for (int j = 0; j < 8; ++j)
                q[j] = rintf(pv[s4 * 8 + j] * rs) * scale;
            union { unsigned u[4]; short8 s; } pk;
            #pragma unroll
            for (int j = 0; j < 4; ++j)
                pk.u[j] = cvt_pk_bf16(q[2 * j], q[2 * j + 1]);
            const int s = qC * 2 + s4;   // 8-elem slot 0..7
            *(short8*)&Bs[base + ((s ^ (rC & 7)) * 8)] = pk.s;
        }
    };

    // ---- prologue ----
    loadC(kt0);                                // +4
    stageA(0, kt0);                            // +4
    VMCNT(4);  quantC();                       // C(kt0) landed (A:4 outstanding)
    loadC(kt0 + 1);                            // +4
    VMCNT(4);                                  // A(kt0) landed; queue = [C':4]
    LGKM0();
    fence_bar();

    int par = 0;
    for (int t = kt0; t < kt1; ++t) {
        const int tn  = (t + 1 < kt1) ? t + 1 : t;        // A stage target (dummy on last)
        const int tn2 = (t + 2 < kt1) ? t + 2 : kt1 - 1;  // C loads (dummy on tail)
        const short* Asc = As[par];

        // issue A(t+1) staging first: full-tile latency slack
        stageA(par ^ 1, tn);         // queue = [C(t+1):4, A:4]

        // ---- MFMA region: As[par] + Bs (single buffer), 32 MFMA/wave ----
        #pragma unroll
        for (int ks = 0; ks < 2; ++ks) {
            bf16x8 bfr[4];
            #pragma unroll
            for (int fn = 0; fn < 4; ++fn) {
                const int r = brow + fn * 16;
                bfr[fn] = *(const bf16x8*)&Bs[r * 64 + (((ks * 4 + qb) ^ (r & 7)) * 8)];
            }
            #pragma unroll
            for (int fm = 0; fm < 4; ++fm) {
                const int r = arow + fm * 16;
                bf16x8 af = *(const bf16x8*)&Asc[r * 64 + (((ks * 4 + qb) ^ (r & 7)) * 8)];
                #pragma unroll
                for (int fn = 0; fn < 4; ++fn)
                    acc[fm][fn] = __builtin_amdgcn_mfma_f32_16x16x32_bf16(
                        af, bfr[fn], acc[fm][fn], 0, 0, 0);
            }
        }
        fence_bar();                 // barrier1: Bs readers done block-wide

        // ---- quant region: write B(t+1) into Bs ----
        VMCNT(4);                    // C(t+1) landed (issued a full tile ago; leaves A:4)
        quantC();
        loadC(tn2);                  // +4
        VMCNT(4);                    // A(t+1) landed (issued at tile top; leaves C(t+2):4)
        LGKM0();                     // quant ds_writes drained
        fence_bar();                 // barrier2: Bs(t+1) + As[par^1] ready
        par ^= 1;
    }

    VMCNT(0);   // drain dummy tail loads

    unsigned short* out = P + (size_t)blockIdx.z * M_DIM * N_DIM;
    #pragma unroll
    for (int fm = 0; fm < 4; ++fm) {
        #pragma unroll
        for (int fn = 0; fn < 4; ++fn) {
            const int col  = n0 + wc * 64 + fn * 16 + (lane & 15);
            const int rowb = m0 + wr * 64 + fm * 16 + (lane >> 4) * 4;
            #pragma unroll
            for (int r = 0; r < 4; ++r) {
                out[(size_t)(rowb + r) * N_DIM + col] = (unsigned short)f2bf(acc[fm][fn][r]);
            }
        }
    }
}

// ---------------- Kernel 3: reduce bf16 split-K partials + bias ----------------
__global__ __launch_bounds__(256) void reduce_out(const unsigned short* __restrict__ P,
                                                  const float* __restrict__ bias,
                                                  float* __restrict__ out,
                                                  int splitk) {
    const size_t total = (size_t)M_DIM * N_DIM;
    for (size_t idx8 = ((size_t)blockIdx.x * 256 + threadIdx.x) * 8;
         idx8 < total;
         idx8 += (size_t)gridDim.x * 256 * 8) {
        const int col = (int)(idx8 % N_DIM);
        float s[8];
        {
            float4 b0 = *(const float4*)(bias + col);
            float4 b1 = *(const float4*)(bias + col + 4);
            s[0] = b0.x; s[1] = b0.y; s[2] = b0.z; s[3] = b0.w;
            s[4] = b1.x; s[5] = b1.y; s[6] = b1.z; s[7] = b1.w;
        }
        for (int sp = 0; sp < splitk; ++sp) {
            short8 p = *(const short8*)(P + (size_t)sp * total + idx8);
            #pragma unroll
            for (int j = 0; j < 8; ++j)
                s[j] += __uint_as_float(((unsigned)(unsigned short)p[j]) << 16);
        }
        float4 o0 = {s[0], s[1], s[2], s[3]};
        float4 o1 = {s[4], s[5], s[6], s[7]};
        *(float4*)(out + idx8) = o0;
        *(float4*)(out + idx8 + 4) = o1;
    }
}

extern "C" void kernel_launch(void* const* d_in, const int* in_sizes, int n_in,
                              void* d_out, int out_size, void* d_ws, size_t ws_size,
                              hipStream_t stream) {
    const float* x    = (const float*)d_in[0];
    const float* wgt  = (const float*)d_in[1];
    const float* bias = (const float*)d_in[2];
    float* out = (float*)d_out;

    char* ws = (char*)d_ws;
    const size_t xb_bytes = (size_t)M_DIM * K_DIM * 2;          // 11,272,192
    short* xb = (short*)ws;
    unsigned short* part = (unsigned short*)(ws + xb_bytes);

    const size_t per_split = (size_t)M_DIM * N_DIM * 2;         // 4 MiB (bf16)
    size_t avail = (ws_size > xb_bytes) ? (ws_size - xb_bytes) : 0;
    // largest splitk in [1,8] that fits, with every split >= 2 K-tiles
    // splitk=8 -> 512 blocks = 2 blocks/CU (necessary per R16, sufficient per R13)
    int splitk = 1, spb = KSTEPS;
    for (int sk = 8; sk >= 1; --sk) {
        if ((size_t)sk * per_split > avail) continue;
        int s = (KSTEPS + sk - 1) / sk;
        int last = KSTEPS - (sk - 1) * s;
        if (last < 2) continue;
        splitk = sk; spb = s;
        break;
    }

    hipLaunchKernelGGL(conv_x, dim3(2048), dim3(256), 0, stream, x, xb);
    hipLaunchKernelGGL(gemm_fq, dim3(N_DIM / 128, M_DIM / 256, splitk), dim3(512), 0, stream,
                       xb, wgt, part, spb);
    hipLaunchKernelGGL(reduce_out, dim3(2048), dim3(256), 0, stream, part, bias, out, splitk);
}

// Round 18
// 83.153 us; speedup vs baseline: 1.3150x; 1.1294x over previous
//
#include <hip/hip_runtime.h>
#include <hip/hip_bf16.h>
#include <stdint.h>

typedef __attribute__((ext_vector_type(8))) short bf16x8;
typedef __attribute__((ext_vector_type(8))) short short8;
typedef __attribute__((ext_vector_type(4))) float f32x4;

#define M_DIM 512
#define N_DIM 4096
#define K_DIM 11008
#define KSTEPS 172   // K_DIM / 64

#define GLOBAL_AS(p) ((const __attribute__((address_space(1))) void*)(p))
#define LDS_AS(p)    ((__attribute__((address_space(3))) void*)(p))

// round-to-nearest-even fp32 -> bf16 bits
__device__ __forceinline__ short f2bf(float f) {
    unsigned u = __float_as_uint(f);
    unsigned r = u + 0x7fff + ((u >> 16) & 1);
    return (short)(r >> 16);
}

__device__ __forceinline__ unsigned cvt_pk_bf16(float lo, float hi) {
    unsigned r;
    asm("v_cvt_pk_bf16_f32 %0, %1, %2" : "=v"(r) : "v"(lo), "v"(hi));
    return r;
}

// pure-VALU DPP quad exchanges
__device__ __forceinline__ float dpp_xor1(float v) {   // quad_perm [1,0,3,2]
    return __int_as_float(__builtin_amdgcn_mov_dpp(__float_as_int(v), 0xB1, 0xf, 0xf, true));
}
__device__ __forceinline__ float dpp_xor2(float v) {   // quad_perm [2,3,0,1]
    return __int_as_float(__builtin_amdgcn_mov_dpp(__float_as_int(v), 0x4E, 0xf, 0xf, true));
}

__device__ __forceinline__ void fence_bar() {
    asm volatile("" ::: "memory");
    __builtin_amdgcn_s_barrier();
    asm volatile("" ::: "memory");
}
#define LGKM0() asm volatile("s_waitcnt lgkmcnt(0)" ::: "memory")
#define VMCNT(n) asm volatile("s_waitcnt vmcnt(" #n ")" ::: "memory")

// ---------------- Kernel 1: x fp32 -> bf16 ----------------
__global__ __launch_bounds__(256) void conv_x(const float* __restrict__ x, short* __restrict__ xb) {
    const long long total = (long long)M_DIM * K_DIM;
    for (long long e0 = ((long long)blockIdx.x * 256 + threadIdx.x) * 8;
         e0 < total;
         e0 += (long long)gridDim.x * 256 * 8) {
        const float4* p = (const float4*)(x + e0);
        float4 v0 = p[0];
        float4 v1 = p[1];
        short8 s;
        s[0] = f2bf(v0.x); s[1] = f2bf(v0.y); s[2] = f2bf(v0.z); s[3] = f2bf(v0.w);
        s[4] = f2bf(v1.x); s[5] = f2bf(v1.y); s[6] = f2bf(v1.z); s[7] = f2bf(v1.w);
        *(short8*)(xb + e0) = s;
    }
}

// ---------------- Kernel 2: fused fake-quant + 256x128 bf16 GEMM (converged best) ----------------
// A: coalesced global_load_lds double-buffer (64KB), XOR-swizzled source.
// B: W fp32 reg-staged (thread = quarter-row, one DPP quad per row) -> pure-VALU quad reduce
//    -> quant -> single-buffer Bs (16KB). Two barriers/tile.
// 8 waves (4M x 2N), per-wave C 64x64 -> acc 64 AGPR, VGPR 64.
// splitk=8 -> 512 blocks = 2 blocks/CU: necessary (R16: 1 block/CU = -20%) and sufficient
// (R13: 4 blocks/CU = no gain; R15: 2x occupancy at same dataflow = no gain).
__global__ __launch_bounds__(512, 4) void gemm_fq(const short* __restrict__ A,
                                                  const float* __restrict__ W,
                                                  unsigned short* __restrict__ P,
                                                  int spb) {
    __shared__ short As[2][256 * 64];
    __shared__ short Bs[128 * 64];
    const int tid  = threadIdx.x;
    const int lane = tid & 63;
    const int w    = tid >> 6;   // 0..7
    const int wr   = w >> 1;     // 0..3 (M)
    const int wc   = w & 1;      // 0..1 (N)
    const int m0   = blockIdx.y * 256;
    const int n0   = blockIdx.x * 128;
    const int kt0  = blockIdx.z * spb;
    const int kt1  = min(kt0 + spb, KSTEPS);   // every split >= 2 tiles by construction

    const int srow = lane >> 3;                      // 0..7 (A staging row within 8-row chunk)
    const int sswz = (lane & 7) ^ srow;              // A staging source swizzle
    const int rC   = tid >> 2;                       // 0..127: B row (4 lanes per row, one quad)
    const int qC   = tid & 3;                        // quarter (16 floats) of the 64-group
    const int arow = wr * 64 + (lane & 15);
    const int brow = wc * 64 + (lane & 15);
    const int qb   = lane >> 4;

    f32x4  acc[4][4] = {};
    float4 C[4];   // one quarter-row of W (16 floats), static indexing

    auto stageA = [&](int d, int kt) {
        #pragma unroll
        for (int i = 0; i < 4; ++i) {
            const int rb = (w * 4 + i) * 8;          // 8 rows per instruction per wave
            __builtin_amdgcn_global_load_lds(
                GLOBAL_AS(A + (size_t)(m0 + rb + srow) * K_DIM + kt * 64 + sswz * 8),
                LDS_AS(&As[d][rb * 64]), 16, 0, 0);
        }
    };
    auto loadC = [&](int kt) {
        const float4* src = (const float4*)(W + (size_t)(n0 + rC) * K_DIM + (size_t)kt * 64 + qC * 16);
        #pragma unroll
        for (int j = 0; j < 4; ++j) C[j] = src[j];
    };
    auto quantC = [&]() {
        const float* pv = (const float*)&C[0];
        float mns[8], mxs[8];
        #pragma unroll
        for (int j = 0; j < 8; ++j) {
            mns[j] = fminf(pv[2 * j], pv[2 * j + 1]);
            mxs[j] = fmaxf(pv[2 * j], pv[2 * j + 1]);
        }
        #pragma unroll
        for (int st = 4; st >= 1; st >>= 1)
            #pragma unroll
            for (int j = 0; j < st; ++j) {
                mns[j] = fminf(mns[j], mns[j + st]);
                mxs[j] = fmaxf(mxs[j], mxs[j + st]);
            }
        // 4 quarter-threads of one row live in one DPP quad: pure-VALU group reduce
        float mn = fminf(mns[0], dpp_xor1(mns[0]));
        mn = fminf(mn, dpp_xor2(mn));
        float mx = fmaxf(mxs[0], dpp_xor1(mxs[0]));
        mx = fmaxf(mx, dpp_xor2(mx));
        float range = fmaxf(mx - mn, 1e-5f);
        float scale = range * (1.0f / 15.0f);
        float rs    = 1.0f / scale;   // one precise div per thread per tile
        // zero-point cancels: w_dq = rint(w/s)*s when no clipping; clamp redundant (proven R6-R17)
        const int base = rC * 64;
        #pragma unroll
        for (int s4 = 0; s4 < 2; ++s4) {
            float q[8];
            #pragma unroll
            for (int j = 0; j < 8; ++j)
                q[j] = rintf(pv[s4 * 8 + j] * rs) * scale;
            union { unsigned u[4]; short8 s; } pk;
            #pragma unroll
            for (int j = 0; j < 4; ++j)
                pk.u[j] = cvt_pk_bf16(q[2 * j], q[2 * j + 1]);
            const int s = qC * 2 + s4;   // 8-elem slot 0..7
            *(short8*)&Bs[base + ((s ^ (rC & 7)) * 8)] = pk.s;
        }
    };

    // ---- prologue ----
    loadC(kt0);                                // +4
    stageA(0, kt0);                            // +4
    VMCNT(4);  quantC();                       // C(kt0) landed (A:4 outstanding)
    loadC(kt0 + 1);                            // +4
    VMCNT(4);                                  // A(kt0) landed; queue = [C':4]
    LGKM0();
    fence_bar();

    int par = 0;
    for (int t = kt0; t < kt1; ++t) {
        const int tn  = (t + 1 < kt1) ? t + 1 : t;        // A stage target (dummy on last)
        const int tn2 = (t + 2 < kt1) ? t + 2 : kt1 - 1;  // C loads (dummy on tail)
        const short* Asc = As[par];

        // issue A(t+1) staging first: full-tile latency slack
        stageA(par ^ 1, tn);         // queue = [C(t+1):4, A:4]

        // ---- MFMA region: As[par] + Bs (single buffer), 32 MFMA/wave ----
        #pragma unroll
        for (int ks = 0; ks < 2; ++ks) {
            bf16x8 bfr[4];
            #pragma unroll
            for (int fn = 0; fn < 4; ++fn) {
                const int r = brow + fn * 16;
                bfr[fn] = *(const bf16x8*)&Bs[r * 64 + (((ks * 4 + qb) ^ (r & 7)) * 8)];
            }
            #pragma unroll
            for (int fm = 0; fm < 4; ++fm) {
                const int r = arow + fm * 16;
                bf16x8 af = *(const bf16x8*)&Asc[r * 64 + (((ks * 4 + qb) ^ (r & 7)) * 8)];
                #pragma unroll
                for (int fn = 0; fn < 4; ++fn)
                    acc[fm][fn] = __builtin_amdgcn_mfma_f32_16x16x32_bf16(
                        af, bfr[fn], acc[fm][fn], 0, 0, 0);
            }
        }
        fence_bar();                 // barrier1: Bs readers done block-wide

        // ---- quant region: write B(t+1) into Bs ----
        VMCNT(4);                    // C(t+1) landed (issued a full tile ago; leaves A:4)
        quantC();
        loadC(tn2);                  // +4
        VMCNT(4);                    // A(t+1) landed (issued at tile top; leaves C(t+2):4)
        LGKM0();                     // quant ds_writes drained
        fence_bar();                 // barrier2: Bs(t+1) + As[par^1] ready
        par ^= 1;
    }

    VMCNT(0);   // drain dummy tail loads

    unsigned short* out = P + (size_t)blockIdx.z * M_DIM * N_DIM;
    #pragma unroll
    for (int fm = 0; fm < 4; ++fm) {
        #pragma unroll
        for (int fn = 0; fn < 4; ++fn) {
            const int col  = n0 + wc * 64 + fn * 16 + (lane & 15);
            const int rowb = m0 + wr * 64 + fm * 16 + (lane >> 4) * 4;
            #pragma unroll
            for (int r = 0; r < 4; ++r) {
                out[(size_t)(rowb + r) * N_DIM + col] = (unsigned short)f2bf(acc[fm][fn][r]);
            }
        }
    }
}

// ---------------- Kernel 3: reduce bf16 split-K partials + bias ----------------
__global__ __launch_bounds__(256) void reduce_out(const unsigned short* __restrict__ P,
                                                  const float* __restrict__ bias,
                                                  float* __restrict__ out,
                                                  int splitk) {
    const size_t total = (size_t)M_DIM * N_DIM;
    for (size_t idx8 = ((size_t)blockIdx.x * 256 + threadIdx.x) * 8;
         idx8 < total;
         idx8 += (size_t)gridDim.x * 256 * 8) {
        const int col = (int)(idx8 % N_DIM);
        float s[8];
        {
            float4 b0 = *(const float4*)(bias + col);
            float4 b1 = *(const float4*)(bias + col + 4);
            s[0] = b0.x; s[1] = b0.y; s[2] = b0.z; s[3] = b0.w;
            s[4] = b1.x; s[5] = b1.y; s[6] = b1.z; s[7] = b1.w;
        }
        for (int sp = 0; sp < splitk; ++sp) {
            short8 p = *(const short8*)(P + (size_t)sp * total + idx8);
            #pragma unroll
            for (int j = 0; j < 8; ++j)
                s[j] += __uint_as_float(((unsigned)(unsigned short)p[j]) << 16);
        }
        float4 o0 = {s[0], s[1], s[2], s[3]};
        float4 o1 = {s[4], s[5], s[6], s[7]};
        *(float4*)(out + idx8) = o0;
        *(float4*)(out + idx8 + 4) = o1;
    }
}

extern "C" void kernel_launch(void* const* d_in, const int* in_sizes, int n_in,
                              void* d_out, int out_size, void* d_ws, size_t ws_size,
                              hipStream_t stream) {
    const float* x    = (const float*)d_in[0];
    const float* wgt  = (const float*)d_in[1];
    const float* bias = (const float*)d_in[2];
    float* out = (float*)d_out;

    char* ws = (char*)d_ws;
    const size_t xb_bytes = (size_t)M_DIM * K_DIM * 2;          // 11,272,192
    short* xb = (short*)ws;
    unsigned short* part = (unsigned short*)(ws + xb_bytes);

    const size_t per_split = (size_t)M_DIM * N_DIM * 2;         // 4 MiB (bf16)
    size_t avail = (ws_size > xb_bytes) ? (ws_size - xb_bytes) : 0;
    // largest splitk in [1,8] that fits, with every split >= 2 K-tiles
    // splitk=8 -> 512 blocks = 2 blocks/CU (necessary per R16, sufficient per R13/R15)
    int splitk = 1, spb = KSTEPS;
    for (int sk = 8; sk >= 1; --sk) {
        if ((size_t)sk * per_split > avail) continue;
        int s = (KSTEPS + sk - 1) / sk;
        int last = KSTEPS - (sk - 1) * s;
        if (last < 2) continue;
        splitk = sk; spb = s;
        break;
    }

    hipLaunchKernelGGL(conv_x, dim3(2048), dim3(256), 0, stream, x, xb);
    hipLaunchKernelGGL(gemm_fq, dim3(N_DIM / 128, M_DIM / 256, splitk), dim3(512), 0, stream,
                       xb, wgt, part, spb);
    hipLaunchKernelGGL(reduce_out, dim3(2048), dim3(256), 0, stream, part, bias, out, splitk);
}